// Round 9
// baseline (147.165 us; speedup 1.0000x reference)
//
#include <hip/hip_runtime.h>
#include <math.h>

#define N_SEQ 1024
#define LL 64
#define DH 256
#define DX 128
#define MQ 8192
#define GG 4096
#define NTYP 64
#define NMEM 262144

typedef __attribute__((ext_vector_type(8))) short short8v;
typedef __attribute__((ext_vector_type(4))) float float4v;

__device__ __forceinline__ float bcast(float v, int l) {
    return __uint_as_float(__builtin_amdgcn_readlane(__float_as_uint(v), l));
}

__device__ __forceinline__ unsigned short f2bf(float x) {
    unsigned int u = __float_as_uint(x);
    u += 0x7FFFu + ((u >> 16) & 1u);   // round-to-nearest-even
    return (unsigned short)(u >> 16);
}

// ---------------- counting-sort based segment sum ---------------------------
__global__ __launch_bounds__(256) void k_hist(const int* __restrict__ grp,
                                              int* __restrict__ cnt) {
    int i = blockIdx.x * 256 + threadIdx.x;
    if (i < NMEM) atomicAdd(&cnt[grp[i]], 1);
}

__global__ __launch_bounds__(1024) void k_scan(const int* __restrict__ cnt,
                                               int* __restrict__ ofs,
                                               int* __restrict__ cur) {
    __shared__ int wsum[16];
    int tid = threadIdx.x;
    int4 c = ((const int4*)cnt)[tid];
    int local = c.x + c.y + c.z + c.w;
    int lane = tid & 63, w = tid >> 6;
    int v = local;
    for (int off = 1; off < 64; off <<= 1) {
        int t = __shfl_up(v, off);
        if (lane >= off) v += t;
    }
    if (lane == 63) wsum[w] = v;
    __syncthreads();
    if (tid < 16) {
        int s = wsum[tid];
        for (int off = 1; off < 16; off <<= 1) {
            int t = __shfl_up(s, off);
            if (tid >= off) s += t;
        }
        wsum[tid] = s;
    }
    __syncthreads();
    int base = (w > 0 ? wsum[w - 1] : 0) + (v - local);
    int4 o;
    o.x = base;
    o.y = base + c.x;
    o.z = o.y + c.y;
    o.w = o.z + c.z;
    ((int4*)ofs)[tid] = o;
    ((int4*)cur)[tid] = o;
}

__global__ __launch_bounds__(256) void k_permute(const int* __restrict__ grp,
                                                 const int* __restrict__ mem,
                                                 int* __restrict__ cur,
                                                 int* __restrict__ tok_sorted) {
    int i = blockIdx.x * 256 + threadIdx.x;
    if (i < NMEM) {
        int g = grp[i];
        int pos = atomicAdd(&cur[g], 1);
        tok_sorted[pos] = mem[i];
    }
}

// z[g] = sum tok_emb rows; fused: zw[g] = z[g] @ Wrel[512:640]
__global__ __launch_bounds__(128) void k_zsum(const int* __restrict__ ofs,
                                              const int* __restrict__ cnt,
                                              const int* __restrict__ tok_sorted,
                                              const float* __restrict__ tok_emb,
                                              const float* __restrict__ Wrel,
                                              float* __restrict__ zw) {
    __shared__ int idxs[128];
    __shared__ float zs[128];
    int g = blockIdx.x;
    int tid = threadIdx.x;
    int start = ofs[g], n = cnt[g];
    float a0 = 0.f, a1 = 0.f, a2 = 0.f, a3 = 0.f;
    for (int j0 = 0; j0 < n; j0 += 128) {
        __syncthreads();
        int rem = n - j0;
        if (tid < rem) idxs[tid] = tok_sorted[start + j0 + tid];
        __syncthreads();
        int kmax = rem < 128 ? rem : 128;
        int k = 0;
        for (; k + 3 < kmax; k += 4) {
            a0 += tok_emb[(size_t)idxs[k + 0] * DX + tid];
            a1 += tok_emb[(size_t)idxs[k + 1] * DX + tid];
            a2 += tok_emb[(size_t)idxs[k + 2] * DX + tid];
            a3 += tok_emb[(size_t)idxs[k + 3] * DX + tid];
        }
        for (; k < kmax; ++k)
            a0 += tok_emb[(size_t)idxs[k] * DX + tid];
    }
    zs[tid] = (a0 + a1) + (a2 + a3);
    __syncthreads();
    if (tid < NTYP) {
        float a2s = 0.f;
#pragma unroll 8
        for (int v = 0; v < DX; ++v)
            a2s += zs[v] * Wrel[(size_t)(512 + v) * NTYP + tid];
        zw[(size_t)g * NTYP + tid] = a2s;
    }
}

// ---------------- build BT[320][512] bf16 and bias[320] ---------------------
__global__ __launch_bounds__(256) void k_wqkb(const float* __restrict__ Wq,
                                              const float* __restrict__ bq,
                                              const float* __restrict__ Wk,
                                              const float* __restrict__ Wrel,
                                              unsigned short* __restrict__ BT,
                                              float* __restrict__ bias) {
    int n = blockIdx.x;
    int tid = threadIdx.x;
    if (n < 256) {
        __shared__ float wk_s[256];
        __shared__ float red[4];
        wk_s[tid] = Wk[(size_t)n * 256 + tid];
        __syncthreads();
#pragma unroll
        for (int jj = 0; jj < 2; ++jj) {
            int j = tid + jj * 256;
            const float* wq = Wq + (size_t)j * 256;
            float acc = 0.f;
#pragma unroll 4
            for (int e = 0; e < 256; ++e) acc += wq[e] * wk_s[e];
            BT[(size_t)n * 512 + j] = f2bf(acc);
        }
        float p = wk_s[tid] * bq[tid];
        for (int o = 32; o; o >>= 1) p += __shfl_xor(p, o);
        if ((tid & 63) == 0) red[tid >> 6] = p;
        __syncthreads();
        if (tid == 0) bias[n] = red[0] + red[1] + red[2] + red[3];
    } else {
        int t = n - 256;
#pragma unroll
        for (int jj = 0; jj < 2; ++jj) {
            int j = tid + jj * 256;
            BT[(size_t)n * 512 + j] = f2bf(Wrel[(size_t)j * NTYP + t]);
        }
        if (tid == 0) bias[n] = 0.f;
    }
}

// ---------------- MFMA GEMM: qk(bf16) + logit partial(fp32) -----------------
__global__ __launch_bounds__(256) void k_gemm(const float* __restrict__ h_grp,
                                              const int* __restrict__ idx,
                                              const int* __restrict__ srcv,
                                              const int* __restrict__ dstv,
                                              const unsigned short* __restrict__ BT,
                                              const float* __restrict__ bias,
                                              unsigned short* __restrict__ qkb,
                                              float* __restrict__ part) {
    __shared__ __align__(16) unsigned short A[16 * 512];
    __shared__ int ns[16], ss[16], dsv[16];
    int bid = blockIdx.x;
    int swz = (bid & 7) * 64 + (bid >> 3);   // 512 blocks, XCD-chunked
    int m0 = swz * 16;
    int tid = threadIdx.x;
    if (tid < 16) {
        int m = m0 + tid;
        ns[tid] = idx[m];
        ss[tid] = srcv[m];
        dsv[tid] = dstv[m];
    }
    __syncthreads();
    {
        int r = tid >> 4;
        int kc = (tid & 15) * 32;
        const float* src = h_grp +
            ((size_t)ns[r] * LL + (kc < 256 ? ss[r] : dsv[r])) * DH + (kc & 255);
        const float4* s4 = (const float4*)src;
        float4 f[8];
#pragma unroll
        for (int j = 0; j < 8; ++j) f[j] = s4[j];
        unsigned short* Arow = A + r * 512;
#pragma unroll
        for (int j = 0; j < 4; ++j) {
            int c = (kc >> 3) + j;
            int cs = (c & ~7) | ((c & 7) ^ (r & 7));
            unsigned short tmp[8];
            float4 lo = f[j * 2], hi = f[j * 2 + 1];
            tmp[0] = f2bf(lo.x); tmp[1] = f2bf(lo.y);
            tmp[2] = f2bf(lo.z); tmp[3] = f2bf(lo.w);
            tmp[4] = f2bf(hi.x); tmp[5] = f2bf(hi.y);
            tmp[6] = f2bf(hi.z); tmp[7] = f2bf(hi.w);
            *(int4*)(Arow + cs * 8) = *(int4*)tmp;
        }
    }
    __syncthreads();

    int w = tid >> 6, lane = tid & 63;
    int r = lane & 15;
    int q = lane >> 4;
    int n0 = w * 80;
    float4v acc[5];
#pragma unroll
    for (int t = 0; t < 5; ++t) {
        float b = bias[n0 + t * 16 + r];
        acc[t] = (float4v){b, b, b, b};
    }
    const unsigned short* Arow = A + r * 512;
#pragma unroll 2
    for (int ks = 0; ks < 16; ++ks) {
        int c = ks * 4 + q;
        int cs = (c & ~7) | ((c & 7) ^ (r & 7));
        short8v a = *(const short8v*)(Arow + cs * 8);
        int kk = ks * 32 + q * 8;
#pragma unroll
        for (int t = 0; t < 5; ++t) {
            int n = n0 + t * 16 + r;
            short8v b = *(const short8v*)(BT + (size_t)n * 512 + kk);
            acc[t] = __builtin_amdgcn_mfma_f32_16x16x32_bf16(a, b, acc[t], 0, 0, 0);
        }
    }
#pragma unroll
    for (int t = 0; t < 5; ++t) {
        int n = n0 + t * 16 + r;
        if (n < 256) {
#pragma unroll
            for (int j = 0; j < 4; ++j)
                qkb[(size_t)(m0 + q * 4 + j) * 256 + n] = f2bf(acc[t][j]);
        } else {
#pragma unroll
            for (int j = 0; j < 4; ++j)
                part[(size_t)(m0 + q * 4 + j) * NTYP + (n - 256)] = acc[t][j];
        }
    }
}

// ---------------- attention: one block per n, MFMA scores -------------------
__global__ __launch_bounds__(256) void k_attn7(const float* __restrict__ h_grp,
                                               const int* __restrict__ idx,
                                               const int* __restrict__ pos2grp,
                                               const int* __restrict__ msk,
                                               const float* __restrict__ zw,
                                               const unsigned short* __restrict__ qkb,
                                               const float* __restrict__ part,
                                               const float* __restrict__ brel,
                                               float* __restrict__ out) {
    __shared__ __align__(16) unsigned short Hs[64][256];   // bf16, chunk-swizzled
    __shared__ __align__(16) unsigned short QKs[16][256];  // bf16, chunk-swizzled
    __shared__ float Ss[64][17];
    __shared__ float zwg[64][68];
    int n = blockIdx.x;
    // query range [start, end) via binary search (idx sorted)
    int lo = 0, hi = MQ;
    while (lo < hi) { int mid = (lo + hi) >> 1; if (idx[mid] < n) lo = mid + 1; else hi = mid; }
    int start = lo;
    hi = MQ;
    while (lo < hi) { int mid = (lo + hi) >> 1; if (idx[mid] < n + 1) lo = mid + 1; else hi = mid; }
    int nq = lo - start;
    if (nq <= 0) return;

    int tid = threadIdx.x;
    int w = tid >> 6, lane = tid & 63;
    int mk = msk[n * LL + lane];       // lane l holds row l (per wave)
    int gv = pos2grp[n * LL + lane];

    // stage H: thread -> row tid>>2, 64 cols
    {
        int r = tid >> 2;
        int cb = (tid & 3) * 64;
        const float4* src = (const float4*)(h_grp + ((size_t)n * LL + r) * DH + cb);
#pragma unroll
        for (int i2 = 0; i2 < 8; ++i2) {
            float4 lo4 = src[i2 * 2], hi4 = src[i2 * 2 + 1];
            unsigned short tmp[8];
            tmp[0] = f2bf(lo4.x); tmp[1] = f2bf(lo4.y);
            tmp[2] = f2bf(lo4.z); tmp[3] = f2bf(lo4.w);
            tmp[4] = f2bf(hi4.x); tmp[5] = f2bf(hi4.y);
            tmp[6] = f2bf(hi4.z); tmp[7] = f2bf(hi4.w);
            int c = (cb >> 3) + i2;
            int cs = c ^ (r & 7);
            *(int4*)(&Hs[r][cs * 8]) = *(int4*)tmp;
        }
    }
    // stage zwg rows (shared by all queries of this n)
    {
        int l = tid >> 2;
        int cb = (tid & 3) * 16;
        int gl = __shfl(gv, l & 63);
        const float4* zsrc = (const float4*)(zw + (size_t)gl * NTYP + cb);
        float4* dst = (float4*)(&zwg[l][cb]);
        dst[0] = zsrc[0]; dst[1] = zsrc[1]; dst[2] = zsrc[2]; dst[3] = zsrc[3];
    }
    float bv = brel[lane];

    for (int t0 = 0; t0 < nq; t0 += 16) {
        int nqt = nq - t0; if (nqt > 16) nqt = 16;
        if (t0 > 0) __syncthreads();   // protect QKs/Ss from prev-tile readers
        // stage QK tile (bf16 rows from qkb; pad with query 0)
        {
            int qi = tid >> 4;
            int cb = (tid & 15) * 16;
            int m = start + t0 + (qi < nqt ? qi : 0);
            const int4* src = (const int4*)(qkb + (size_t)m * 256 + cb);
            int4 v0 = src[0], v1 = src[1];
            int c = cb >> 3;
            *(int4*)(&QKs[qi][(c ^ (qi & 7)) * 8]) = v0;
            *(int4*)(&QKs[qi][((c + 1) ^ (qi & 7)) * 8]) = v1;
        }
        __syncthreads();
        // S = H @ QK^T : wave w computes l-tile w (16 l x 16 queries)
        {
            float4v sacc = (float4v){0.f, 0.f, 0.f, 0.f};
            int arow = 16 * w + (lane & 15);
            int qi = lane & 15;
            int kb = lane >> 4;
#pragma unroll
            for (int ks = 0; ks < 8; ++ks) {
                int c = ks * 4 + kb;
                short8v a = *(const short8v*)(&Hs[arow][(c ^ (arow & 7)) * 8]);
                short8v b = *(const short8v*)(&QKs[qi][(c ^ (qi & 7)) * 8]);
                sacc = __builtin_amdgcn_mfma_f32_16x16x32_bf16(a, b, sacc, 0, 0, 0);
            }
#pragma unroll
            for (int j = 0; j < 4; ++j) {
                int l = 16 * w + (lane >> 4) * 4 + j;
                int mkl = __shfl(mk, l);
                Ss[l][qi] = mkl ? sacc[j] * 0.0625f : -INFINITY;
            }
        }
        __syncthreads();
        // softmax + ctx + out; wave w handles queries w, w+4, w+8, w+12
        for (int qq = w; qq < nqt; qq += 4) {
            float sv = Ss[lane][qq];
            float mx = sv;
#pragma unroll
            for (int o = 32; o; o >>= 1) mx = fmaxf(mx, __shfl_xor(mx, o));
            float pe = __expf(sv - mx);
            float sum = pe;
#pragma unroll
            for (int o = 32; o; o >>= 1) sum += __shfl_xor(sum, o);
            float attn = pe / sum;
            float acc = 0.f;
#pragma unroll 16
            for (int l = 0; l < 64; ++l)
                acc += bcast(attn, l) * zwg[l][lane];
            int m = start + t0 + qq;
            out[(size_t)m * NTYP + lane] = part[(size_t)m * NTYP + lane] + bv + acc;
        }
    }
}

extern "C" void kernel_launch(void* const* d_in, const int* in_sizes, int n_in,
                              void* d_out, int out_size, void* d_ws, size_t ws_size,
                              hipStream_t stream) {
    const int*   mem     = (const int*)d_in[0];
    const int*   grp     = (const int*)d_in[1];
    const int*   pos2grp = (const int*)d_in[2];
    const float* h_grp   = (const float*)d_in[3];
    const int*   msk     = (const int*)d_in[4];
    const int*   idx     = (const int*)d_in[5];
    const int*   srcv    = (const int*)d_in[6];
    const int*   dstv    = (const int*)d_in[7];
    // d_in[8] = typ (unused by the reference)
    const float* tok_emb = (const float*)d_in[9];
    const float* Wq      = (const float*)d_in[10];
    const float* bq      = (const float*)d_in[11];
    const float* Wk      = (const float*)d_in[12];
    const float* bk      = (const float*)d_in[13];  // softmax-invariant: unused
    const float* Wrel    = (const float*)d_in[14];
    const float* brel    = (const float*)d_in[15];
    float* out = (float*)d_out;
    (void)bk;

    float* ws = (float*)d_ws;
    size_t off = 0;
    float* zw   = ws + off; off += (size_t)GG * NTYP;       // 262144
    unsigned short* qkb = (unsigned short*)(ws + off); off += (size_t)MQ * 256 / 2; // bf16
    float* part = ws + off; off += (size_t)MQ * NTYP;       // 524288
    float* bias = ws + off; off += 320;
    unsigned short* BT = (unsigned short*)(ws + off); off += (320 * 512) / 2;
    int* cnt        = (int*)(ws + off); off += GG;
    int* ofs        = (int*)(ws + off); off += GG;
    int* cur        = (int*)(ws + off); off += GG;
    int* tok_sorted = (int*)(ws + off); off += NMEM;

    // segment-sum via counting sort (no float atomics), fused zw projection
    hipMemsetAsync(cnt, 0, GG * sizeof(int), stream);
    k_hist<<<NMEM / 256, 256, 0, stream>>>(grp, cnt);
    k_scan<<<1, 1024, 0, stream>>>(cnt, ofs, cur);
    k_permute<<<NMEM / 256, 256, 0, stream>>>(grp, mem, cur, tok_sorted);
    k_zsum<<<GG, 128, 0, stream>>>(ofs, cnt, tok_sorted, tok_emb, Wrel, zw);

    // folded weights -> bf16 B^T [320][512] + bias[320]
    k_wqkb<<<320, 256, 0, stream>>>(Wq, bq, Wk, Wrel, BT, bias);

    // MFMA GEMM: qk (bf16, 256 cols) + logit partial (fp32, 64 cols)
    k_gemm<<<MQ / 16, 256, 0, stream>>>(h_grp, idx, srcv, dstv, BT, bias, qkb, part);

    // per-n MFMA attention
    k_attn7<<<N_SEQ, 256, 0, stream>>>(h_grp, idx, pos2grp, msk, zw, qkb, part, brel, out);
}